// Round 6
// baseline (34577.084 us; speedup 1.0000x reference)
//
#include <hip/hip_runtime.h>
#include <hip/hip_bf16.h>
#include <stdint.h>

// Problem dims
#define B_   16
#define T_   4096
#define F_   47
#define HID_ 64
#define CH_  256
#define TG_  1024   // T/4
#define G3_  768    // 3*CH

using bf16x8 = __attribute__((ext_vector_type(8))) short;  // 8 bf16 (4 VGPRs)
using f32x4  = __attribute__((ext_vector_type(4))) float;  // 4 fp32 acc
using f16x8  = __attribute__((ext_vector_type(8))) _Float16;
using h2     = __attribute__((ext_vector_type(2))) _Float16;

__device__ __forceinline__ short f2bf(float f) {
    union { float f; uint32_t u; } v; v.f = f;
    uint32_t u = v.u;
    uint32_t r = (u + 0x7fffu + ((u >> 16) & 1u)) >> 16;   // RNE
    return (short)r;
}
__device__ __forceinline__ float bf2f(short s) {
    union { uint32_t u; float f; } v; v.u = ((uint32_t)(uint16_t)s) << 16;
    return v.f;
}
__device__ __forceinline__ float fast_tanh(float x) {
    float e = __expf(2.f * x);           // inf-safe
    return 1.f - 2.f / (e + 1.f);
}
__device__ __forceinline__ float fast_sigmoid(float x) {
    return 1.f / (1.f + __expf(-x));
}

#if __has_builtin(__builtin_amdgcn_fdot2)
#define FDOT2(a, b, c) __builtin_amdgcn_fdot2((a), (b), (c), false)
#else
__device__ __forceinline__ float fdot2_emul(h2 a, h2 b, float c) {
    return c + (float)a[0] * (float)b[0] + (float)a[1] * (float)b[1];
}
#define FDOT2(a, b, c) fdot2_emul((a), (b), (c))
#endif

// DPP quad-perm add: butterfly reduce across the 4 lanes of a quad (no LDS).
template <int CTRL>
__device__ __forceinline__ float dpp_add(float x) {
    union { float f; int i; } a, b;
    a.f = x;
    b.i = __builtin_amdgcn_update_dpp(0, a.i, CTRL, 0xf, 0xf, true);
    return x + b.f;
}

#if __has_builtin(__builtin_amdgcn_global_load_lds)
#define HAS_GLL 1
__device__ __forceinline__ void gl_lds16(const void* g, void* l) {
    __builtin_amdgcn_global_load_lds(
        (const __attribute__((address_space(1))) uint32_t*)g,
        (__attribute__((address_space(3))) uint32_t*)l, 16, 0, 0);
}
#else
#define HAS_GLL 0
#endif

// ---------------------------------------------------------------------------
// K1: conv1 (pointwise 47->64) + tanh, fp32 VALU, writes c1 as bf16
__global__ __launch_bounds__(256) void k1_conv1(const float* __restrict__ feat,
        const float* __restrict__ W1, const float* __restrict__ b1,
        short* __restrict__ c1) {
    __shared__ float sW[47 * 64];
    __shared__ float sF[4 * 47];
    int tid = threadIdx.x;
    int b = blockIdx.x >> 10, t0 = (blockIdx.x & 1023) * 4;
    if (tid < 188) sF[tid] = feat[((size_t)b * T_ + t0) * 47 + tid];
    for (int i = tid; i < 47 * 64; i += 256) {
        int f = i >> 6, h = i & 63;
        sW[i] = W1[h * 47 + f];
    }
    __syncthreads();
    int fr = tid >> 6, h = tid & 63;
    float acc = b1[h];
    #pragma unroll
    for (int f = 0; f < 47; ++f)
        acc += sF[fr * 47 + f] * sW[f * 64 + h];
    c1[((size_t)b * T_ + t0 + fr) * 64 + h] = f2bf(fast_tanh(acc));
}

// ---------------------------------------------------------------------------
// Weight prep (bf16 B^T layouts for the prelude GEMMs)
__global__ __launch_bounds__(256) void k_prep(const float* __restrict__ W2,
        const float* __restrict__ Wt, const float* __restrict__ Wih_f,
        short* __restrict__ W2t, short* __restrict__ Wtt, short* __restrict__ Wih) {
    int idx = blockIdx.x * 256 + threadIdx.x;
    if (idx < 256 * 512) {
        int o = idx >> 9, i = idx & 511, d = i >> 8, jj = i & 255;
        W2t[idx] = f2bf(W2[(size_t)o * 512 + jj * 2 + d]);
    }
    {
        int n = idx >> 8, ic = idx & 255, o = n & 255, kp = n >> 8;
        Wtt[idx] = f2bf(Wt[(size_t)ic * 1024 + o * 4 + kp]);
    }
    if (idx < G3_ * CH_)
        Wih[idx] = f2bf(Wih_f[idx]);
}

// ---------------------------------------------------------------------------
// K2: conv2 (k=2 causal) as GEMM M=16384,K=512,N=256 + tanh.
__global__ __launch_bounds__(256) void k2_conv2(const short* __restrict__ c1,
        const short* __restrict__ W2t, const float* __restrict__ b2,
        short* __restrict__ y2) {
    int tid = threadIdx.x, w = tid >> 6, l = tid & 63;
    int lane16 = l & 15, quad = l >> 4;
    int mt = blockIdx.x * 4 + w;
    int row = mt * 16 + lane16;
    int tg = row & 1023;
    const short* Arow = c1 + (size_t)row * 256 - 256;
    bf16x8 zero8 = {0,0,0,0,0,0,0,0};
    bf16x8 af[16];
    #pragma unroll
    for (int kt = 0; kt < 16; ++kt) {
        int i0 = kt * 32 + quad * 8;
        bool masked = (tg == 0) && (kt < 8);
        const short* p = masked ? c1 : (Arow + i0);
        bf16x8 v = *(const bf16x8*)p;
        af[kt] = masked ? zero8 : v;
    }
    #pragma unroll
    for (int nt = 0; nt < 16; ++nt) {
        int n = nt * 16 + lane16;
        f32x4 acc = {0.f, 0.f, 0.f, 0.f};
        const short* Brow = W2t + (size_t)n * 512 + quad * 8;
        #pragma unroll
        for (int kt = 0; kt < 16; ++kt) {
            bf16x8 bf = *(const bf16x8*)(Brow + kt * 32);
            acc = __builtin_amdgcn_mfma_f32_16x16x32_bf16(af[kt], bf, acc, 0, 0, 0);
        }
        float bias = b2[n];
        #pragma unroll
        for (int r = 0; r < 4; ++r) {
            int mrow = mt * 16 + quad * 4 + r;
            y2[(size_t)mrow * 256 + n] = f2bf(fast_tanh(acc[r] + bias));
        }
    }
}

// ---------------------------------------------------------------------------
// K3a: tconv as GEMM M=16384,K=256,N=1024 + tanh -> c3 bf16.
__global__ __launch_bounds__(256) void k3a_tconv(const short* __restrict__ y2,
        const short* __restrict__ Wtt, const float* __restrict__ bt,
        short* __restrict__ c3) {
    int tid = threadIdx.x, w = tid >> 6, l = tid & 63;
    int lane16 = l & 15, quad = l >> 4;
    int mt = blockIdx.x;
    int row = mt * 16 + lane16;
    const short* Arow = y2 + (size_t)row * 256 + quad * 8;
    bf16x8 af[8];
    #pragma unroll
    for (int kt = 0; kt < 8; ++kt) af[kt] = *(const bf16x8*)(Arow + kt * 32);
    #pragma unroll
    for (int nt2 = 0; nt2 < 16; ++nt2) {
        int n = (w * 16 + nt2) * 16 + lane16;
        f32x4 acc = {0.f, 0.f, 0.f, 0.f};
        const short* Brow = Wtt + (size_t)n * 256 + quad * 8;
        #pragma unroll
        for (int kt = 0; kt < 8; ++kt) {
            bf16x8 bf = *(const bf16x8*)(Brow + kt * 32);
            acc = __builtin_amdgcn_mfma_f32_16x16x32_bf16(af[kt], bf, acc, 0, 0, 0);
        }
        int kp = n >> 8, o = n & 255;
        float bias = bt[o];
        #pragma unroll
        for (int r = 0; r < 4; ++r) {
            int mrow = mt * 16 + quad * 4 + r;
            int bb = mrow >> 10, tgg = mrow & 1023;
            c3[(((size_t)bb * TG_ + tgg) * 4 + kp) * 256 + o] =
                f2bf(fast_tanh(acc[r] + bias));
        }
    }
}

// ---------------------------------------------------------------------------
// K3b: x-projection GEMM M=65536,K=256,N=768 (+b_ih) -> gates bf16.
// gates[(b*T+t)*768 + n]
__global__ __launch_bounds__(256) void k3b_xproj(const short* __restrict__ c3,
        const short* __restrict__ Wih, const float* __restrict__ b_ih,
        short* __restrict__ gates) {
    int tid = threadIdx.x, w = tid >> 6, l = tid & 63;
    int lane16 = l & 15, quad = l >> 4;
    int mt = blockIdx.x;
    int row = mt * 16 + lane16;
    const short* Arow = c3 + (size_t)row * 256 + quad * 8;
    bf16x8 af[8];
    #pragma unroll
    for (int kt = 0; kt < 8; ++kt) af[kt] = *(const bf16x8*)(Arow + kt * 32);
    #pragma unroll
    for (int nt2 = 0; nt2 < 12; ++nt2) {
        int n = (w * 12 + nt2) * 16 + lane16;
        f32x4 acc = {0.f, 0.f, 0.f, 0.f};
        const short* Brow = Wih + (size_t)n * 256 + quad * 8;
        #pragma unroll
        for (int kt = 0; kt < 8; ++kt) {
            bf16x8 bf = *(const bf16x8*)(Brow + kt * 32);
            acc = __builtin_amdgcn_mfma_f32_16x16x32_bf16(af[kt], bf, acc, 0, 0, 0);
        }
        float bias = b_ih[n];
        #pragma unroll
        for (int r = 0; r < 4; ++r) {
            int mrow = mt * 16 + quad * 4 + r;
            gates[(size_t)mrow * G3_ + n] = f2bf(acc[r] + bias);
        }
    }
}

// ---------------------------------------------------------------------------
// K4: persistent GRU, hybrid REG+LDS weights — 1 block/batch, 1024 thr.
// ROOT-CAUSE FIX for rounds 0-5: whenever total register demand exceeds the
// unified-file budget, the backend splits the budget ~50/50 arch/acc and
// spills overflow to AGPRs (observed: arch=budget/2 in r0 (128 of 256) and
// r3-r5 (64 of 128)); each fdot2 on an AGPR-resident weight then pays a
// v_accvgpr_read (~2x VALU issue). Demand (96 wreg + ~35) was always just
// over budget. This version CUTS DEMAND below 128 structurally:
//   * 25% of weights (8 of 32 h2 per row) live in LDS (w_lds, 96KB),
//     re-read each step via lane-linear ds_read_b128 (conflict-free);
//     LDS pipe cost ~875 cy/step hides under the ~1200 cy VALU phase.
//   * wreg[3][24] = 72 regs; total demand ~110 <= 128 budget -> no spill,
//     no AGPRs, no tax. VALIDATION: VGPR_Count must print ~100-115.
//   * LDS total 140KB forces 1 block/CU -> exactly 4 waves/EU -> the
//     128-reg budget is unambiguous to the backend (no attribute games).
// Kept from r5 (race-clean, conflict-free): single barrier/step, quad-DPP
// butterfly + in-place ew on q==0 lanes, padded hq_s dbuf, ob dbuf,
// 8-step gate ring via global_load_lds.
__global__ __launch_bounds__(1024)
void k4_gru_dot2(const float* __restrict__ W_hh,
        const float* __restrict__ b_hh, const short* __restrict__ gates,
        float* __restrict__ out) {
    __shared__ __align__(16) short gxb[2][8][G3_];   // 24KB gate ring (bf16)
    __shared__ __align__(16) float ob[2][8 * 256];   // 16KB out staging (dbuf)
    __shared__ __align__(16) short hq_s[2][4 * 72];  // 1.1KB h f16, padded quarters
    __shared__ __align__(16) h2 w_lds[6][1024][4];   // 96KB spilled weights
                                                     // [rk*2+j2][tid][p2]

    int tid = threadIdx.x, l = tid & 63, w = tid >> 6;
    int q = tid & 3, n0 = tid >> 2;                  // n0 in 0..255
    int b = blockIdx.x;

    // ---- W_hh: j<24 -> registers (72 h2), j in [24,32) -> LDS (24 h2)
    h2 wreg[3][24];
    #pragma unroll
    for (int k = 0; k < 3; ++k) {
        const float2* row = (const float2*)(W_hh + ((size_t)(n0 + k * 256)) * 256 + q * 64);
        #pragma unroll
        for (int j = 0; j < 24; ++j) {
            float2 v = row[j];
            h2 p; p[0] = (_Float16)v.x; p[1] = (_Float16)v.y;
            wreg[k][j] = p;
        }
        #pragma unroll
        for (int j2 = 0; j2 < 2; ++j2) {
            union { f16x8 v8; h2 p[4]; } wv;
            #pragma unroll
            for (int p2 = 0; p2 < 4; ++p2) {
                float2 v = row[24 + j2 * 4 + p2];
                h2 p; p[0] = (_Float16)v.x; p[1] = (_Float16)v.y;
                wv.p[p2] = p;
            }
            *(f16x8*)&w_lds[k * 2 + j2][tid][0] = wv.v8;
        }
    }

    // biases for this thread's channel (used only by q==0 lanes)
    float bhr = b_hh[n0], bhz = b_hh[256 + n0], bhn = b_hh[512 + n0];
    float h_reg = 0.f;
    if (tid < 288) hq_s[0][tid] = 0;                 // h = 0 (f16), buf 0

    const short* gbase = gates + (size_t)b * T_ * G3_;
    const char* gbytes = (const char*)gbase;

    // prologue: steps 0..7 -> ring half 0 (12KB = waves 0..11, 1KB each)
#if HAS_GLL
    if (w < 12) {
        char* dst = (char*)&gxb[0][0][0];
        gl_lds16(gbytes + w * 1024 + l * 16, dst + w * 1024);
    }
#else
    {
        const uint32_t* g32 = (const uint32_t*)gbytes;
        uint32_t* d = (uint32_t*)&gxb[0][0][0];
        #pragma unroll
        for (int i = 0; i < 3; ++i) d[tid + i * 1024] = g32[tid + i * 1024];
    }
#endif
    __syncthreads();   // also covers w_lds writes

    float* outb = out + (size_t)b * T_ * CH_;
    for (int s = 0; s < T_; ++s) {
        bool grp0 = ((s & 7) == 0) && (s + 8 < T_);
#if HAS_GLL
        if (grp0 && w < 12) {   // async stage next 8 steps into other ring half
            const char* src = gbytes + (size_t)(s + 8) * 1536;
            char* dst = (char*)&gxb[((s >> 3) + 1) & 1][0][0];
            gl_lds16(src + w * 1024 + l * 16, dst + w * 1024);
        }
#else
        if (grp0) {
            const uint32_t* src = (const uint32_t*)(gbytes + (size_t)(s + 8) * 1536);
            uint32_t* d = (uint32_t*)&gxb[((s >> 3) + 1) & 1][0][0];
            #pragma unroll
            for (int i = 0; i < 3; ++i) d[tid + i * 1024] = src[tid + i * 1024];
        }
#endif

        // ---- dot2 phase: 96 fdot2/thread (72 reg-weights + 24 LDS-weights)
        float acc0 = 0.f, acc1 = 0.f, acc2 = 0.f;
        const short* hb = &hq_s[s & 1][q * 72];
        #pragma unroll 2
        for (int g2 = 0; g2 < 6; ++g2) {
            union { f16x8 v8; h2 p[4]; } hc;
            hc.v8 = *(const f16x8*)(hb + g2 * 8);
            #pragma unroll
            for (int p2 = 0; p2 < 4; ++p2) {
                h2 hv = hc.p[p2];
                acc0 = FDOT2(wreg[0][g2 * 4 + p2], hv, acc0);
                acc1 = FDOT2(wreg[1][g2 * 4 + p2], hv, acc1);
                acc2 = FDOT2(wreg[2][g2 * 4 + p2], hv, acc2);
            }
        }
        #pragma unroll
        for (int j2 = 0; j2 < 2; ++j2) {
            union { f16x8 v8; h2 p[4]; } hc, w0, w1, w2;
            hc.v8 = *(const f16x8*)(hb + 48 + j2 * 8);
            w0.v8 = *(const f16x8*)&w_lds[j2][tid][0];
            w1.v8 = *(const f16x8*)&w_lds[2 + j2][tid][0];
            w2.v8 = *(const f16x8*)&w_lds[4 + j2][tid][0];
            #pragma unroll
            for (int p2 = 0; p2 < 4; ++p2) {
                h2 hv = hc.p[p2];
                acc0 = FDOT2(w0.p[p2], hv, acc0);
                acc1 = FDOT2(w1.p[p2], hv, acc1);
                acc2 = FDOT2(w2.p[p2], hv, acc2);
            }
        }

        // ---- quad butterfly: full K-sum in every quad lane (no LDS)
        acc0 = dpp_add<0xB1>(acc0); acc0 = dpp_add<0x4E>(acc0);
        acc1 = dpp_add<0xB1>(acc1); acc1 = dpp_add<0x4E>(acc1);
        acc2 = dpp_add<0xB1>(acc2); acc2 = dpp_add<0x4E>(acc2);

        // ---- in-place elementwise on q==0 lanes (channel n0)
        if (q == 0) {
            const short* gx = &gxb[(s >> 3) & 1][s & 7][0];
            float xr = bf2f(gx[n0]), xz = bf2f(gx[256 + n0]), xn = bf2f(gx[512 + n0]);
            float r = fast_sigmoid(xr + acc0 + bhr);
            float z = fast_sigmoid(xz + acc1 + bhz);
            float nn = fast_tanh(xn + r * (acc2 + bhn));
            h_reg = (1.f - z) * nn + z * h_reg;
            union { _Float16 f; short u; } cv; cv.f = (_Float16)h_reg;
            hq_s[(s + 1) & 1][(n0 >> 6) * 72 + (n0 & 63)] = cv.u;
            ob[(s >> 3) & 1][(s & 7) * 256 + n0] = h_reg;
        }
        __syncthreads();   // single barrier per step

        // ---- out flush once per 8 steps, coalesced f32x4 (waves 0-7),
        // reads the buffer just completed; next group writes the other one.
        if ((s & 7) == 7 && tid < 512) {
            f32x4 v = *(const f32x4*)&ob[(s >> 3) & 1][tid * 4];
            *(f32x4*)&outb[(size_t)(s - 7 + (tid >> 6)) * 256 + (tid & 63) * 4] = v;
        }
    }
}

// ---------------------------------------------------------------------------
extern "C" void kernel_launch(void* const* d_in, const int* in_sizes, int n_in,
                              void* d_out, int out_size, void* d_ws, size_t ws_size,
                              hipStream_t stream) {
    const float* feat  = (const float*)d_in[0];
    const float* W1    = (const float*)d_in[1];
    const float* b1    = (const float*)d_in[2];
    const float* W2    = (const float*)d_in[3];
    const float* b2    = (const float*)d_in[4];
    const float* Wt    = (const float*)d_in[5];
    const float* bt    = (const float*)d_in[6];
    const float* Wih_f = (const float*)d_in[7];
    const float* Whh   = (const float*)d_in[8];
    const float* bih   = (const float*)d_in[9];
    const float* bhh   = (const float*)d_in[10];
    float* out = (float*)d_out;

    // ws layout (135.4 MB):
    //   [0, 33.5M)      c3 bf16 (c1 aliases first 8.4M; c1 dead after K2)
    //   [33.5M, 134.2M) gates bf16 (y2 aliases first 8.4M; y2 dead after K3a)
    //   [134.2M, ...)   W2t / Wtt / Wih bf16
    char* ws = (char*)d_ws;
    short* c3    = (short*)(ws);
    short* c1    = (short*)(ws);
    short* gates = (short*)(ws + 33554432);
    short* y2    = (short*)(ws + 33554432);
    short* W2t   = (short*)(ws + 134217728);
    short* Wtt   = (short*)(ws + 134217728 + 262144);
    short* Wih   = (short*)(ws + 134217728 + 262144 + 524288);

    k1_conv1   <<<16384, 256, 0, stream>>>(feat, W1, b1, c1);
    k_prep     <<<1024, 256, 0, stream>>>(W2, Wt, Wih_f, W2t, Wtt, Wih);
    k2_conv2   <<<256,  256, 0, stream>>>(c1, W2t, b2, y2);
    k3a_tconv  <<<1024, 256, 0, stream>>>(y2, Wtt, bt, c3);      // kills c1
    k3b_xproj  <<<4096, 256, 0, stream>>>(c3, Wih, bih, gates);  // kills y2
    k4_gru_dot2<<<16,   1024, 0, stream>>>(Whh, bhh, gates, out);
}

// Round 7
// 6099.410 us; speedup vs baseline: 5.6689x; 5.6689x over previous
//
#include <hip/hip_runtime.h>
#include <hip/hip_bf16.h>
#include <stdint.h>

// Problem dims
#define B_   16
#define T_   4096
#define F_   47
#define HID_ 64
#define CH_  256
#define TG_  1024   // T/4
#define G3_  768    // 3*CH

using bf16x8 = __attribute__((ext_vector_type(8))) short;  // 8 bf16 (4 VGPRs)
using f32x4  = __attribute__((ext_vector_type(4))) float;  // 4 fp32 acc
using f16x8  = __attribute__((ext_vector_type(8))) _Float16;
using h2     = __attribute__((ext_vector_type(2))) _Float16;

__device__ __forceinline__ short f2bf(float f) {
    union { float f; uint32_t u; } v; v.f = f;
    uint32_t u = v.u;
    uint32_t r = (u + 0x7fffu + ((u >> 16) & 1u)) >> 16;   // RNE
    return (short)r;
}
__device__ __forceinline__ float bf2f(short s) {
    union { uint32_t u; float f; } v; v.u = ((uint32_t)(uint16_t)s) << 16;
    return v.f;
}
__device__ __forceinline__ float fast_tanh(float x) {
    float e = __expf(2.f * x);           // inf-safe
    return 1.f - 2.f / (e + 1.f);
}
__device__ __forceinline__ float fast_sigmoid(float x) {
    return 1.f / (1.f + __expf(-x));
}

#if __has_builtin(__builtin_amdgcn_fdot2)
#define FDOT2(a, b, c) __builtin_amdgcn_fdot2((a), (b), (c), false)
#else
__device__ __forceinline__ float fdot2_emul(h2 a, h2 b, float c) {
    return c + (float)a[0] * (float)b[0] + (float)a[1] * (float)b[1];
}
#define FDOT2(a, b, c) fdot2_emul((a), (b), (c))
#endif

// DPP quad-perm add: butterfly reduce across the 4 lanes of a quad (no LDS).
template <int CTRL>
__device__ __forceinline__ float dpp_add(float x) {
    union { float f; int i; } a, b;
    a.f = x;
    b.i = __builtin_amdgcn_update_dpp(0, a.i, CTRL, 0xf, 0xf, true);
    return x + b.f;
}

#if __has_builtin(__builtin_amdgcn_global_load_lds)
#define HAS_GLL 1
__device__ __forceinline__ void gl_lds16(const void* g, void* l) {
    __builtin_amdgcn_global_load_lds(
        (const __attribute__((address_space(1))) uint32_t*)g,
        (__attribute__((address_space(3))) uint32_t*)l, 16, 0, 0);
}
#else
#define HAS_GLL 0
#endif

// ---------------------------------------------------------------------------
// K1: conv1 (pointwise 47->64) + tanh, fp32 VALU, writes c1 as bf16
__global__ __launch_bounds__(256) void k1_conv1(const float* __restrict__ feat,
        const float* __restrict__ W1, const float* __restrict__ b1,
        short* __restrict__ c1) {
    __shared__ float sW[47 * 64];
    __shared__ float sF[4 * 47];
    int tid = threadIdx.x;
    int b = blockIdx.x >> 10, t0 = (blockIdx.x & 1023) * 4;
    if (tid < 188) sF[tid] = feat[((size_t)b * T_ + t0) * 47 + tid];
    for (int i = tid; i < 47 * 64; i += 256) {
        int f = i >> 6, h = i & 63;
        sW[i] = W1[h * 47 + f];
    }
    __syncthreads();
    int fr = tid >> 6, h = tid & 63;
    float acc = b1[h];
    #pragma unroll
    for (int f = 0; f < 47; ++f)
        acc += sF[fr * 47 + f] * sW[f * 64 + h];
    c1[((size_t)b * T_ + t0 + fr) * 64 + h] = f2bf(fast_tanh(acc));
}

// ---------------------------------------------------------------------------
// Weight prep (bf16 B^T layouts for the prelude GEMMs)
__global__ __launch_bounds__(256) void k_prep(const float* __restrict__ W2,
        const float* __restrict__ Wt, const float* __restrict__ Wih_f,
        short* __restrict__ W2t, short* __restrict__ Wtt, short* __restrict__ Wih) {
    int idx = blockIdx.x * 256 + threadIdx.x;
    if (idx < 256 * 512) {
        int o = idx >> 9, i = idx & 511, d = i >> 8, jj = i & 255;
        W2t[idx] = f2bf(W2[(size_t)o * 512 + jj * 2 + d]);
    }
    {
        int n = idx >> 8, ic = idx & 255, o = n & 255, kp = n >> 8;
        Wtt[idx] = f2bf(Wt[(size_t)ic * 1024 + o * 4 + kp]);
    }
    if (idx < G3_ * CH_)
        Wih[idx] = f2bf(Wih_f[idx]);
}

// ---------------------------------------------------------------------------
// K2: conv2 (k=2 causal) as GEMM M=16384,K=512,N=256 + tanh.
__global__ __launch_bounds__(256) void k2_conv2(const short* __restrict__ c1,
        const short* __restrict__ W2t, const float* __restrict__ b2,
        short* __restrict__ y2) {
    int tid = threadIdx.x, w = tid >> 6, l = tid & 63;
    int lane16 = l & 15, quad = l >> 4;
    int mt = blockIdx.x * 4 + w;
    int row = mt * 16 + lane16;
    int tg = row & 1023;
    const short* Arow = c1 + (size_t)row * 256 - 256;
    bf16x8 zero8 = {0,0,0,0,0,0,0,0};
    bf16x8 af[16];
    #pragma unroll
    for (int kt = 0; kt < 16; ++kt) {
        int i0 = kt * 32 + quad * 8;
        bool masked = (tg == 0) && (kt < 8);
        const short* p = masked ? c1 : (Arow + i0);
        bf16x8 v = *(const bf16x8*)p;
        af[kt] = masked ? zero8 : v;
    }
    #pragma unroll
    for (int nt = 0; nt < 16; ++nt) {
        int n = nt * 16 + lane16;
        f32x4 acc = {0.f, 0.f, 0.f, 0.f};
        const short* Brow = W2t + (size_t)n * 512 + quad * 8;
        #pragma unroll
        for (int kt = 0; kt < 16; ++kt) {
            bf16x8 bf = *(const bf16x8*)(Brow + kt * 32);
            acc = __builtin_amdgcn_mfma_f32_16x16x32_bf16(af[kt], bf, acc, 0, 0, 0);
        }
        float bias = b2[n];
        #pragma unroll
        for (int r = 0; r < 4; ++r) {
            int mrow = mt * 16 + quad * 4 + r;
            y2[(size_t)mrow * 256 + n] = f2bf(fast_tanh(acc[r] + bias));
        }
    }
}

// ---------------------------------------------------------------------------
// K3a: tconv as GEMM M=16384,K=256,N=1024 + tanh -> c3 bf16.
__global__ __launch_bounds__(256) void k3a_tconv(const short* __restrict__ y2,
        const short* __restrict__ Wtt, const float* __restrict__ bt,
        short* __restrict__ c3) {
    int tid = threadIdx.x, w = tid >> 6, l = tid & 63;
    int lane16 = l & 15, quad = l >> 4;
    int mt = blockIdx.x;
    int row = mt * 16 + lane16;
    const short* Arow = y2 + (size_t)row * 256 + quad * 8;
    bf16x8 af[8];
    #pragma unroll
    for (int kt = 0; kt < 8; ++kt) af[kt] = *(const bf16x8*)(Arow + kt * 32);
    #pragma unroll
    for (int nt2 = 0; nt2 < 16; ++nt2) {
        int n = (w * 16 + nt2) * 16 + lane16;
        f32x4 acc = {0.f, 0.f, 0.f, 0.f};
        const short* Brow = Wtt + (size_t)n * 256 + quad * 8;
        #pragma unroll
        for (int kt = 0; kt < 8; ++kt) {
            bf16x8 bf = *(const bf16x8*)(Brow + kt * 32);
            acc = __builtin_amdgcn_mfma_f32_16x16x32_bf16(af[kt], bf, acc, 0, 0, 0);
        }
        int kp = n >> 8, o = n & 255;
        float bias = bt[o];
        #pragma unroll
        for (int r = 0; r < 4; ++r) {
            int mrow = mt * 16 + quad * 4 + r;
            int bb = mrow >> 10, tgg = mrow & 1023;
            c3[(((size_t)bb * TG_ + tgg) * 4 + kp) * 256 + o] =
                f2bf(fast_tanh(acc[r] + bias));
        }
    }
}

// ---------------------------------------------------------------------------
// K3b: x-projection GEMM M=65536,K=256,N=768 (+b_ih) -> gates bf16.
// gates[(b*T+t)*768 + n]
__global__ __launch_bounds__(256) void k3b_xproj(const short* __restrict__ c3,
        const short* __restrict__ Wih, const float* __restrict__ b_ih,
        short* __restrict__ gates) {
    int tid = threadIdx.x, w = tid >> 6, l = tid & 63;
    int lane16 = l & 15, quad = l >> 4;
    int mt = blockIdx.x;
    int row = mt * 16 + lane16;
    const short* Arow = c3 + (size_t)row * 256 + quad * 8;
    bf16x8 af[8];
    #pragma unroll
    for (int kt = 0; kt < 8; ++kt) af[kt] = *(const bf16x8*)(Arow + kt * 32);
    #pragma unroll
    for (int nt2 = 0; nt2 < 12; ++nt2) {
        int n = (w * 12 + nt2) * 16 + lane16;
        f32x4 acc = {0.f, 0.f, 0.f, 0.f};
        const short* Brow = Wih + (size_t)n * 256 + quad * 8;
        #pragma unroll
        for (int kt = 0; kt < 8; ++kt) {
            bf16x8 bf = *(const bf16x8*)(Brow + kt * 32);
            acc = __builtin_amdgcn_mfma_f32_16x16x32_bf16(af[kt], bf, acc, 0, 0, 0);
        }
        float bias = b_ih[n];
        #pragma unroll
        for (int r = 0; r < 4; ++r) {
            int mrow = mt * 16 + quad * 4 + r;
            gates[(size_t)mrow * G3_ + n] = f2bf(acc[r] + bias);
        }
    }
}

// ---------------------------------------------------------------------------
// K4: persistent GRU, HYBRID MFMA+dot2 — 1 block/batch, 512 thr, 8 waves.
// After 6 rounds: the allocator always grants arch = half the per-wave
// budget when AGPRs are live, so any all-VALU design with >64-96 weight
// regs pays a per-use AGPR-read tax. This version splits the matvec so
// each side's registers live where they're free:
//   * rows 0..511 (r,z gates) -> MATRIX pipe. mfma_f32_16x16x32_f16 with
//     h broadcast to all 16 B-cols (any D-col = matvec). Weights live as
//     persistent A-fragments: wave w owns M-tiles 4w..4w+3 -> 4x8 f16x8
//     = 128 regs -> exactly the AGPR half (MFMA reads AGPRs natively,
//     ZERO tax). 256 mfma/step/CU = ~1240 cy on the matrix pipe.
//   * rows 512..767 (n gate) -> VALU dot2. Thread (q=tid&3, i=tid>>2)
//     owns K-quarter [64q,64q+64) of channels {2i,2i+1}: wreg[2][32]
//     = 64 regs -> fits the 128-arch half WITH margin -> no demotion.
//     ~140 VALU inst/wave/step issues in the mfma pipe's slot gaps
//     (separate pipes, m114) -> nearly free.
// All loops FULLY unrolled (r6 lesson: partial unroll -> runtime index
// -> scratch). launch_bounds(512,2): 2 waves/EU, 256 budget, 128/128
// split matches demand (arch ~110 / agpr 128) exactly.
// Epilogue = r0's proven structure: part LDS, 2 barriers, ew on tid<256,
// padded hq_s dbuf, ob 8-step flush, 8-step gate ring via gl_lds16.
__global__ __launch_bounds__(512, 2) void k4_gru_hyb(const float* __restrict__ W_hh,
        const float* __restrict__ b_hh, const short* __restrict__ gates,
        float* __restrict__ out) {
    __shared__ __align__(16) short gxb[2][8][G3_];   // 24KB gate ring (bf16)
    __shared__ __align__(16) float part[G3_];        // 3KB gate sums
    __shared__ __align__(16) float ob[8 * 256];      // 8KB out staging
    __shared__ __align__(16) short hq_s[2][4 * 72];  // h f16, padded quarters, dbuf

    int tid = threadIdx.x, l = tid & 63, w = tid >> 6;
    int lane16 = l & 15, quad = l >> 4;
    int q = tid & 3, i2 = tid >> 2;                  // dot2 coords, i2 in 0..127
    int b = blockIdx.x;

    // ---- MFMA A-fragments: rows 0..511, wave w -> M-tiles 4w+mt.
    // A-frag layout (16x16x32): lane holds A[row=lane16][k=quad*8+e].
    f16x8 afrag[4][8];
    #pragma unroll
    for (int mt = 0; mt < 4; ++mt) {
        const float* wrow = W_hh + (size_t)((w * 4 + mt) * 16 + lane16) * 256 + quad * 8;
        #pragma unroll
        for (int kt = 0; kt < 8; ++kt) {
            const float4* p = (const float4*)(wrow + kt * 32);
            float4 x = p[0], y = p[1];
            f16x8 f;
            f[0] = (_Float16)x.x; f[1] = (_Float16)x.y;
            f[2] = (_Float16)x.z; f[3] = (_Float16)x.w;
            f[4] = (_Float16)y.x; f[5] = (_Float16)y.y;
            f[6] = (_Float16)y.z; f[7] = (_Float16)y.w;
            afrag[mt][kt] = f;
        }
    }

    // ---- dot2 weights: n-gate rows 512+2*i2, 512+2*i2+1, K-quarter q. 64 regs.
    h2 wreg[2][32];
    #pragma unroll
    for (int rr = 0; rr < 2; ++rr) {
        const float2* row = (const float2*)(W_hh + (size_t)(512 + 2 * i2 + rr) * 256 + q * 64);
        #pragma unroll
        for (int j = 0; j < 32; ++j) {
            float2 v = row[j];
            h2 p; p[0] = (_Float16)v.x; p[1] = (_Float16)v.y;
            wreg[rr][j] = p;
        }
    }

    float h_reg = 0.f, bhr = 0.f, bhz = 0.f, bhn = 0.f;
    if (tid < 256) {
        bhr = b_hh[tid]; bhz = b_hh[256 + tid]; bhn = b_hh[512 + tid];
    }
    if (tid < 288) hq_s[0][tid] = 0;                 // h = 0 (f16), buf 0

    const short* gbase = gates + (size_t)b * T_ * G3_;
    const char* gbytes = (const char*)gbase;

    // prologue: steps 0..7 -> ring half 0 (12KB)
#if HAS_GLL
    {
        char* dst = (char*)&gxb[0][0][0];
        gl_lds16(gbytes + w * 1024 + l * 16, dst + w * 1024);
        if (w < 4) gl_lds16(gbytes + (8 + w) * 1024 + l * 16, dst + (8 + w) * 1024);
    }
#else
    {
        const uint32_t* g32 = (const uint32_t*)gbytes;
        uint32_t* d = (uint32_t*)&gxb[0][0][0];
        #pragma unroll
        for (int i = 0; i < 6; ++i) d[tid + i * 512] = g32[tid + i * 512];
    }
#endif
    __syncthreads();

    float* outb = out + (size_t)b * T_ * CH_;
    for (int s = 0; s < T_; ++s) {
        bool grp0 = ((s & 7) == 0) && (s + 8 < T_);
#if HAS_GLL
        if (grp0) {   // async stage next 8 steps; latency hides under mfma phase
            const char* src = gbytes + (size_t)(s + 8) * 1536;
            char* dst = (char*)&gxb[((s >> 3) + 1) & 1][0][0];
            gl_lds16(src + w * 1024 + l * 16, dst + w * 1024);
            if (w < 4) gl_lds16(src + (8 + w) * 1024 + l * 16, dst + (8 + w) * 1024);
        }
#else
        uint32_t pf[6];
        if (grp0) {
            const uint32_t* src = (const uint32_t*)(gbytes + (size_t)(s + 8) * 1536);
            #pragma unroll
            for (int i = 0; i < 6; ++i) pf[i] = src[tid + i * 512];
        }
#endif

        // ---- MFMA phase: r,z gate matvec on the matrix pipe.
        // B-frag = h broadcast: lane needs h[kt*32 + quad*8 .. +8] (uniform
        // within each quad group -> LDS broadcast read, conflict-free).
        f32x4 acc4[4];
        #pragma unroll
        for (int mt = 0; mt < 4; ++mt) acc4[mt] = (f32x4){0.f, 0.f, 0.f, 0.f};
        #pragma unroll
        for (int kt = 0; kt < 8; ++kt) {
            int k0 = kt * 32 + quad * 8;
            f16x8 hb = *(const f16x8*)&hq_s[s & 1][(k0 >> 6) * 72 + (k0 & 63)];
            #pragma unroll
            for (int mt = 0; mt < 4; ++mt)
                acc4[mt] = __builtin_amdgcn_mfma_f32_16x16x32_f16(afrag[mt][kt], hb, acc4[mt], 0, 0, 0);
        }

        // ---- dot2 phase: n gate on the VALU (issues in mfma slot gaps).
        float a0 = 0.f, a1 = 0.f;
        const short* hb2 = &hq_s[s & 1][q * 72];
        #pragma unroll
        for (int g2 = 0; g2 < 8; ++g2) {
            union { f16x8 v8; h2 p[4]; } hc;
            hc.v8 = *(const f16x8*)(hb2 + g2 * 8);
            #pragma unroll
            for (int p2 = 0; p2 < 4; ++p2) {
                h2 hv = hc.p[p2];
                a0 = FDOT2(wreg[0][g2 * 4 + p2], hv, a0);
                a1 = FDOT2(wreg[1][g2 * 4 + p2], hv, a1);
            }
        }
        a0 = dpp_add<0xB1>(a0); a0 = dpp_add<0x4E>(a0);
        a1 = dpp_add<0xB1>(a1); a1 = dpp_add<0x4E>(a1);

        // ---- publish partials. D layout: col=lane16 (all equal), row=quad*4+r.
        if (lane16 == 0) {
            #pragma unroll
            for (int mt = 0; mt < 4; ++mt)
                *(f32x4*)&part[(w * 4 + mt) * 16 + quad * 4] = acc4[mt];
        }
        if (q == 0) {
            float2 nn2; nn2.x = a0; nn2.y = a1;
            *(float2*)&part[512 + 2 * i2] = nn2;
        }
        __syncthreads();   // b1

#if !HAS_GLL
        if (grp0) {
            uint32_t* d = (uint32_t*)&gxb[((s >> 3) + 1) & 1][0][0];
            #pragma unroll
            for (int i = 0; i < 6; ++i) d[tid + i * 512] = pf[i];
        }
#endif
        // ---- elementwise on threads < 256 (one wave per SIMD)
        if (tid < 256) {
            const short* gx = &gxb[(s >> 3) & 1][s & 7][0];
            float gr = part[tid];
            float gz = part[256 + tid];
            float gn = part[512 + tid];
            float xr = bf2f(gx[tid]), xz = bf2f(gx[256 + tid]), xn = bf2f(gx[512 + tid]);
            float r = fast_sigmoid(xr + gr + bhr);
            float z = fast_sigmoid(xz + gz + bhz);
            float nn = fast_tanh(xn + r * (gn + bhn));
            h_reg = (1.f - z) * nn + z * h_reg;
            union { _Float16 f; short u; } cv; cv.f = (_Float16)h_reg;
            hq_s[(s + 1) & 1][(tid >> 6) * 72 + (tid & 63)] = cv.u;
            ob[(s & 7) * 256 + tid] = h_reg;
        }
        __syncthreads();   // b2

        // ---- out flush once per 8 steps, coalesced f32x4
        if ((s & 7) == 7) {
            f32x4 v = *(const f32x4*)&ob[tid * 4];
            *(f32x4*)&outb[(size_t)(s - 7 + (tid >> 6)) * 256 + (tid & 63) * 4] = v;
        }
    }
}

// ---------------------------------------------------------------------------
extern "C" void kernel_launch(void* const* d_in, const int* in_sizes, int n_in,
                              void* d_out, int out_size, void* d_ws, size_t ws_size,
                              hipStream_t stream) {
    const float* feat  = (const float*)d_in[0];
    const float* W1    = (const float*)d_in[1];
    const float* b1    = (const float*)d_in[2];
    const float* W2    = (const float*)d_in[3];
    const float* b2    = (const float*)d_in[4];
    const float* Wt    = (const float*)d_in[5];
    const float* bt    = (const float*)d_in[6];
    const float* Wih_f = (const float*)d_in[7];
    const float* Whh   = (const float*)d_in[8];
    const float* bih   = (const float*)d_in[9];
    const float* bhh   = (const float*)d_in[10];
    float* out = (float*)d_out;

    // ws layout (135.4 MB):
    //   [0, 33.5M)      c3 bf16 (c1 aliases first 8.4M; c1 dead after K2)
    //   [33.5M, 134.2M) gates bf16 (y2 aliases first 8.4M; y2 dead after K3a)
    //   [134.2M, ...)   W2t / Wtt / Wih bf16
    char* ws = (char*)d_ws;
    short* c3    = (short*)(ws);
    short* c1    = (short*)(ws);
    short* gates = (short*)(ws + 33554432);
    short* y2    = (short*)(ws + 33554432);
    short* W2t   = (short*)(ws + 134217728);
    short* Wtt   = (short*)(ws + 134217728 + 262144);
    short* Wih   = (short*)(ws + 134217728 + 262144 + 524288);

    k1_conv1  <<<16384, 256, 0, stream>>>(feat, W1, b1, c1);
    k_prep    <<<1024, 256, 0, stream>>>(W2, Wt, Wih_f, W2t, Wtt, Wih);
    k2_conv2  <<<256,  256, 0, stream>>>(c1, W2t, b2, y2);
    k3a_tconv <<<1024, 256, 0, stream>>>(y2, Wtt, bt, c3);      // kills c1
    k3b_xproj <<<4096, 256, 0, stream>>>(c3, Wih, bih, gates);  // kills y2
    k4_gru_hyb<<<16,   512, 0, stream>>>(Whh, bhh, gates, out);
}